// Round 5
// baseline (359.599 us; speedup 1.0000x reference)
//
#include <hip/hip_runtime.h>
#include <hip/hip_bf16.h>

#define NN 2048
#define FIN 256
#define FOUT 256
#define HH 8

typedef short bhalf8 __attribute__((ext_vector_type(8)));   // 8 bf16
typedef float f32x4  __attribute__((ext_vector_type(4)));   // MFMA acc

__device__ __forceinline__ unsigned short f2b(float f) {
    __hip_bfloat16 h = __float2bfloat16(f);
    return *reinterpret_cast<unsigned short*>(&h);
}
__device__ __forceinline__ float b2f(unsigned short u) {
    __hip_bfloat16 h = *reinterpret_cast<__hip_bfloat16*>(&u);
    return __bfloat162float(h);
}

// ------------------- K1: qk, vtb (bf16 transpose direct), zero D/rowsum/rowsq
__global__ __launch_bounds__(256) void k1_qkv(
    const float* __restrict__ x, const float* __restrict__ Wq,
    const float* __restrict__ Wk, const float* __restrict__ Wv,
    unsigned short* __restrict__ vtb, float* __restrict__ qk,
    float* __restrict__ D, float* __restrict__ rowsum, float* __restrict__ rowsq)
{
    const int ib = blockIdx.x * 4;
    const int t  = threadIdx.x;
    {   // zero accumulators (stream-ordered before k2/k5; makes pipeline idempotent)
        const int tp = blockIdx.x*256 + t;
        if      (tp < 16384) D[tp] = 0.f;
        else if (tp < 18432) rowsum[tp - 16384] = 0.f;
        else if (tp < 20480) rowsq [tp - 18432] = 0.f;
    }
    __shared__ float xs[4][FIN];
    __shared__ float part[256];
    #pragma unroll
    for (int n = 0; n < 4; ++n) xs[n][t] = x[(long)(ib+n)*FIN + t];
    __syncthreads();
    float a0 = 0.f, a1 = 0.f, a2 = 0.f, a3 = 0.f;
    #pragma unroll 4
    for (int c = 0; c < FIN; ++c) {
        const float wv = Wv[c*FOUT + t];
        a0 = fmaf(xs[0][c], wv, a0); a1 = fmaf(xs[1][c], wv, a1);
        a2 = fmaf(xs[2][c], wv, a2); a3 = fmaf(xs[3][c], wv, a3);
    }
    ushort4 uv;
    uv.x = f2b(a0 * 0.0625f); uv.y = f2b(a1 * 0.0625f);
    uv.z = f2b(a2 * 0.0625f); uv.w = f2b(a3 * 0.0625f);
    *(ushort4*)&vtb[(long)t*NN + ib] = uv;
    {
        const int n = t >> 6, h = t & 7, seg = (t >> 3) & 7;
        float a = 0.f;
        for (int c = seg*32; c < seg*32 + 32; ++c)
            a = fmaf(xs[n][c], Wq[c*HH + h] + Wk[c*HH + h], a);
        part[t] = a;
    }
    __syncthreads();
    if (t < 32) {
        const int n = t >> 3, h = t & 7;
        float a = 0.f;
        #pragma unroll
        for (int s2 = 0; s2 < 8; ++s2) a += part[n*64 + s2*8 + h];
        qk[(ib+n)*HH + h] = a * (0.0625f * 0.35355339059327373f); // *scale/sqrt(8)
    }
}

// ------------------------------------------------- K2: denoms + f-field + dd
__global__ __launch_bounds__(256) void k2_denom(
    const float* __restrict__ bond, const float* __restrict__ dist,
    const float* __restrict__ deg, const float* __restrict__ qk,
    const float* __restrict__ wb, const float* __restrict__ wbc,
    const float* __restrict__ wg, float* __restrict__ D,
    unsigned short* __restrict__ fbuf, unsigned short* __restrict__ ddb)
{
    const float cb = wb[0] * wbc[0];
    const float cg = wg[0];
    const int t  = threadIdx.x;
    const int tx = t & 63;              // j-quad
    const int ty = t >> 6;              // 0..3 (i-subtile, 8 i each)
    const int j0 = blockIdx.x * 256;
    const int i0 = blockIdx.y * 32;
    const int j  = j0 + tx*4;
    __shared__ float qs[32*8];          // 1 KB
    __shared__ float red[4][2048];      // 32 KB
    for (int p = t; p < 256; p += 256) qs[p] = qk[i0*8 + p];
    __syncthreads();
    float acc[4][8];
    #pragma unroll
    for (int jj = 0; jj < 4; ++jj)
        #pragma unroll
        for (int h = 0; h < 8; ++h) acc[jj][h] = 0.f;
    const int ibase = i0 + ty*8;
    #pragma unroll
    for (int ii = 0; ii < 8; ++ii) {
        const long idx = (long)(ibase + ii)*NN + j;
        const float4 dv = *(const float4*)&dist[idx];
        const float4 bv = *(const float4*)&bond[idx];
        const float4 gv = *(const float4*)&deg[idx];
        ushort4 fb, db;
        fb.x = f2b((gv.x > 0.f) ? fmaf(cb, bv.x, cg*dv.x) : -__builtin_inff());
        fb.y = f2b((gv.y > 0.f) ? fmaf(cb, bv.y, cg*dv.y) : -__builtin_inff());
        fb.z = f2b((gv.z > 0.f) ? fmaf(cb, bv.z, cg*dv.z) : -__builtin_inff());
        fb.w = f2b((gv.w > 0.f) ? fmaf(cb, bv.w, cg*dv.w) : -__builtin_inff());
        db.x = f2b(-dv.x * gv.x); db.y = f2b(-dv.y * gv.y);
        db.z = f2b(-dv.z * gv.z); db.w = f2b(-dv.w * gv.w);
        *(ushort4*)&fbuf[idx] = fb;
        *(ushort4*)&ddb[idx]  = db;
        float s[4];
        s[0] = b2f(fb.x); s[1] = b2f(fb.y); s[2] = b2f(fb.z); s[3] = b2f(fb.w);
        const float* qrow = &qs[(ty*8 + ii)*8];
        #pragma unroll
        for (int h = 0; h < 8; ++h) {
            const float q = qrow[h];
            #pragma unroll
            for (int jj = 0; jj < 4; ++jj) {
                float r = q + s[jj];
                r = fmaxf(r, 0.2f*r);       // leaky_relu(r, 0.2)
                acc[jj][h] += __expf(r);    // masked: exp(-inf) = 0
            }
        }
    }
    #pragma unroll
    for (int jj = 0; jj < 4; ++jj)
        #pragma unroll
        for (int h = 0; h < 8; ++h) red[ty][(tx*4 + jj)*8 + h] = acc[jj][h];
    __syncthreads();
    for (int p = t; p < 2048; p += 256) {
        const float ssum = red[0][p] + red[1][p] + red[2][p] + red[3][p];
        atomicAdd(&D[j0*8 + p], ssum);
    }
}

// --------------------------- K3: attn_mean -> bf16 (tile 32i x 256j, grid 512)
__global__ __launch_bounds__(256) void k3_attnmean(
    const unsigned short* __restrict__ fbuf, const float* __restrict__ qk,
    const float* __restrict__ D, unsigned short* __restrict__ amb)
{
    const int t  = threadIdx.x;
    const int tx = t & 63;
    const int ty = t >> 6;
    const int j0 = blockIdx.x * 256;
    const int i0 = blockIdx.y * 32;
    const int j  = j0 + tx*4;
    __shared__ float qs[32*8];
    for (int p = t; p < 256; p += 256) qs[p] = qk[i0*8 + p];
    __syncthreads();
    float invD[4][8];
    #pragma unroll
    for (int jj = 0; jj < 4; ++jj)
        #pragma unroll
        for (int h = 0; h < 8; ++h)
            invD[jj][h] = 0.125f / fmaxf(D[(j + jj)*8 + h], 1e-30f);
    const int ibase = i0 + ty*8;
    #pragma unroll
    for (int ii = 0; ii < 8; ++ii) {
        const long idx = (long)(ibase + ii)*NN + j;
        const ushort4 fb = *(const ushort4*)&fbuf[idx];
        float s[4];
        s[0] = b2f(fb.x); s[1] = b2f(fb.y); s[2] = b2f(fb.z); s[3] = b2f(fb.w);
        float o[4] = {0.f, 0.f, 0.f, 0.f};
        const float* qrow = &qs[(ty*8 + ii)*8];
        #pragma unroll
        for (int h = 0; h < 8; ++h) {
            const float q = qrow[h];
            #pragma unroll
            for (int jj = 0; jj < 4; ++jj) {
                float r = q + s[jj];
                r = fmaxf(r, 0.2f*r);
                o[jj] = fmaf(__expf(r), invD[jj][h], o[jj]);  // masked -> 0
            }
        }
        ushort4 ob;
        ob.x = f2b(o[0]); ob.y = f2b(o[1]); ob.z = f2b(o[2]); ob.w = f2b(o[3]);
        *(ushort4*)&amb[idx] = ob;
    }
}

// --------------- K4: aggregated = amb @ vtb^T (full K) + elu -> out0, unb
__global__ __launch_bounds__(256) void k4_aggr(
    const unsigned short* __restrict__ amb,
    const unsigned short* __restrict__ vtb,
    float* __restrict__ out0, unsigned short* __restrict__ unb)
{
    const int w = threadIdx.x >> 6, lane = threadIdx.x & 63;
    const int vw = blockIdx.x*4 + w;            // [0,2048)
    const int it = vw >> 4;                     // i-tile [0,128)
    const int f0 = (vw & 15) * 16;              // f-tile
    const int lm = lane & 15, lq = lane >> 4;
    const unsigned short* arow = &amb[(long)(it*16 + lm)*NN + lq*8];
    const unsigned short* brow = &vtb[(long)(f0 + lm)*NN + lq*8];
    f32x4 acc = {0.f, 0.f, 0.f, 0.f};
    #pragma unroll 4
    for (int kk = 0; kk < NN; kk += 32) {
        const bhalf8 a = *(const bhalf8*)&arow[kk];
        const bhalf8 b = *(const bhalf8*)&brow[kk];
        acc = __builtin_amdgcn_mfma_f32_16x16x32_bf16(a, b, acc, 0, 0, 0);
    }
    #pragma unroll
    for (int r = 0; r < 4; ++r) {
        const int i = it*16 + lq*4 + r;         // C/D: row=(l>>4)*4+reg
        const int f = f0 + lm;                  //      col=l&15
        float s = acc[r];
        s = (s > 0.f) ? s : (__expf(s) - 1.f);
        out0[(long)i*FOUT + f] = s;
        unb [(long)i*FOUT + f] = f2b(s);
    }
}

// -------- K5: sim = un@un^T via MFMA; c0 = bf16(sigmoid(sim)*ddb); row stats
__global__ __launch_bounds__(256) void k5_sim(
    const unsigned short* __restrict__ unb, const unsigned short* __restrict__ ddb,
    unsigned short* __restrict__ c0,
    float* __restrict__ rowsum, float* __restrict__ rowsq)
{
    const int i0 = blockIdx.y * 64;
    const int j0 = blockIdx.x * 64;
    const int w  = threadIdx.x >> 6;
    const int l  = threadIdx.x & 63;
    const int lm = l & 15, lq = l >> 4;
    const int iw = i0 + w*16;
    f32x4 acc[4] = {f32x4{0,0,0,0}, f32x4{0,0,0,0}, f32x4{0,0,0,0}, f32x4{0,0,0,0}};
    for (int kk = 0; kk < FOUT; kk += 32) {
        const bhalf8 a = *(const bhalf8*)&unb[(long)(iw + lm)*FOUT + kk + lq*8];
        #pragma unroll
        for (int c = 0; c < 4; ++c) {
            const bhalf8 b = *(const bhalf8*)&unb[(long)(j0 + c*16 + lm)*FOUT + kk + lq*8];
            acc[c] = __builtin_amdgcn_mfma_f32_16x16x32_bf16(a, b, acc[c], 0, 0, 0);
        }
    }
    float srow[4] = {0.f,0.f,0.f,0.f}, qrow[4] = {0.f,0.f,0.f,0.f};
    #pragma unroll
    for (int c = 0; c < 4; ++c) {
        #pragma unroll
        for (int r = 0; r < 4; ++r) {
            const int i = iw + lq*4 + r;
            const int j = j0 + c*16 + lm;
            const long idx = (long)i*NN + j;
            const float sg = 1.f / (1.f + __expf(-acc[c][r]));
            const float val = sg * b2f(ddb[idx]);        // ddb = -dist*deg
            c0[idx] = f2b(val);
            srow[r] += val;
            qrow[r] = fmaf(val, val, qrow[r]);
        }
    }
    #pragma unroll
    for (int r = 0; r < 4; ++r) {
        #pragma unroll
        for (int m = 8; m >= 1; m >>= 1) {
            srow[r] += __shfl_xor(srow[r], m, 64);
            qrow[r] += __shfl_xor(qrow[r], m, 64);
        }
        if (lm == 0) {
            atomicAdd(&rowsum[iw + lq*4 + r], srow[r]);
            atomicAdd(&rowsq [iw + lq*4 + r], qrow[r]);
        }
    }
}

// -------- K7: conn = norm(c0) + norm(c0)^T; stats computed from rowsum/rowsq
__global__ __launch_bounds__(256) void k7_conn(
    const unsigned short* __restrict__ c0, const float* __restrict__ rowsum,
    const float* __restrict__ rowsq, float* __restrict__ out1)
{
    const int i0 = blockIdx.y * 64;
    const int j0 = blockIdx.x * 64;
    const int t  = threadIdx.x;
    __shared__ float LT[64][68];     // LT[i_local][j_local] = c0[j0+jl][i0+il]
    __shared__ float mui[64], rii[64], muj[64], rsj[64];
    const int r  = t >> 4;
    const int c4 = (t & 15) * 4;
    if (t < 64) {
        const float m = rowsum[j0 + t] * (1.f/NN);
        muj[t] = m;
        rsj[t] = rsqrtf(rowsq[j0 + t]*(1.f/NN) - m*m + 1e-5f);
    } else if (t < 128) {
        const int rr = t - 64;
        const float m = rowsum[i0 + rr] * (1.f/NN);
        mui[rr] = m;
        rii[rr] = rsqrtf(rowsq[i0 + rr]*(1.f/NN) - m*m + 1e-5f);
    }
    #pragma unroll
    for (int p = 0; p < 4; ++p) {
        const int jl = r + p*16;
        const ushort4 q = *(const ushort4*)&c0[(long)(j0 + jl)*NN + i0 + c4];
        LT[c4+0][jl] = b2f(q.x); LT[c4+1][jl] = b2f(q.y);
        LT[c4+2][jl] = b2f(q.z); LT[c4+3][jl] = b2f(q.w);
    }
    __syncthreads();
    #pragma unroll
    for (int p = 0; p < 4; ++p) {
        const int rr = r + p*16;
        const int i  = i0 + rr;
        const ushort4 xb = *(const ushort4*)&c0[(long)i*NN + j0 + c4];
        const float mi = mui[rr], ri = rii[rr];
        float4 o;
        o.x = (b2f(xb.x) - mi)*ri + (LT[rr][c4+0] - muj[c4+0])*rsj[c4+0];
        o.y = (b2f(xb.y) - mi)*ri + (LT[rr][c4+1] - muj[c4+1])*rsj[c4+1];
        o.z = (b2f(xb.z) - mi)*ri + (LT[rr][c4+2] - muj[c4+2])*rsj[c4+2];
        o.w = (b2f(xb.w) - mi)*ri + (LT[rr][c4+3] - muj[c4+3])*rsj[c4+3];
        *(float4*)&out1[(long)i*NN + j0 + c4] = o;
    }
}

extern "C" void kernel_launch(void* const* d_in, const int* in_sizes, int n_in,
                              void* d_out, int out_size, void* d_ws, size_t ws_size,
                              hipStream_t stream)
{
    const float* x    = (const float*)d_in[0];
    const float* dist = (const float*)d_in[1];
    const float* bond = (const float*)d_in[2];
    // d_in[3] edge_direction: unused (only l=0 component couples; Y_0 = 1)
    const float* deg  = (const float*)d_in[4];
    const float* Wq   = (const float*)d_in[5];
    const float* Wk   = (const float*)d_in[6];
    const float* Wv   = (const float*)d_in[7];
    const float* wb   = (const float*)d_in[8];
    const float* wbc  = (const float*)d_in[9];
    const float* wg   = (const float*)d_in[10];

    float* out0 = (float*)d_out;            // updated_nodes: 2048*256 fp32
    float* out1 = out0 + (size_t)NN*FOUT;   // conn: 2048*2048 fp32

    char* w = (char*)d_ws;
    unsigned short* fbuf_c0 = (unsigned short*)(w);           //  8,388,608 B
    unsigned short* amb  = (unsigned short*)(w +  8388608);   //  8,388,608 B
    unsigned short* ddb  = (unsigned short*)(w + 16777216);   //  8,388,608 B
    unsigned short* vtb  = (unsigned short*)(w + 25165824);   //  1,048,576 B
    unsigned short* unb  = (unsigned short*)(w + 26214400);   //  1,048,576 B
    float* qk      = (float*)(w + 27262976);                  //     65,536 B
    float* D       = (float*)(w + 27328512);                  //     65,536 B
    float* rowsum  = (float*)(w + 27394048);                  //      8,192 B
    float* rowsq   = (float*)(w + 27402240);                  //      8,192 B

    // INSTRUMENTATION ROUND: run the (idempotent) pipeline TWICE.
    // k1 re-zeros D/rowsum/rowsq, all other buffers are deterministic
    // overwrites, so outputs are bit-identical. Delta vs round 4 dur_us
    // equals the total silicon time of the 6 kernels + 6 launch gaps.
    for (int rep = 0; rep < 2; ++rep) {
        k1_qkv<<<NN/4, 256, 0, stream>>>(x, Wq, Wk, Wv, vtb, qk, D, rowsum, rowsq);
        dim3 g23(NN/256, NN/32);
        k2_denom<<<g23, 256, 0, stream>>>(bond, dist, deg, qk, wb, wbc, wg, D, fbuf_c0, ddb);
        k3_attnmean<<<g23, 256, 0, stream>>>(fbuf_c0, qk, D, amb);
        k4_aggr<<<NN/4, 256, 0, stream>>>(amb, vtb, out0, unb);
        dim3 g5(NN/64, NN/64);
        k5_sim<<<g5, 256, 0, stream>>>(unb, ddb, fbuf_c0, rowsum, rowsq);
        k7_conn<<<g5, 256, 0, stream>>>(fbuf_c0, rowsum, rowsq, out1);
    }
}

// Round 6
// 235.950 us; speedup vs baseline: 1.5240x; 1.5240x over previous
//
#include <hip/hip_runtime.h>
#include <hip/hip_bf16.h>

#define NN 2048
#define FIN 256
#define FOUT 256
#define HH 8

typedef short bhalf8 __attribute__((ext_vector_type(8)));   // 8 bf16
typedef float f32x4  __attribute__((ext_vector_type(4)));   // MFMA acc

__device__ __forceinline__ unsigned short f2b(float f) {
    __hip_bfloat16 h = __float2bfloat16(f);
    return *reinterpret_cast<unsigned short*>(&h);
}
__device__ __forceinline__ float b2f(unsigned short u) {
    __hip_bfloat16 h = *reinterpret_cast<__hip_bfloat16*>(&u);
    return __bfloat162float(h);
}

// ------------------- K1: qk, vtb (bf16 transpose direct), zero D8/rowsum/rowsq
__global__ __launch_bounds__(256) void k1_qkv(
    const float* __restrict__ x, const float* __restrict__ Wq,
    const float* __restrict__ Wk, const float* __restrict__ Wv,
    unsigned short* __restrict__ vtb, float* __restrict__ qk,
    float* __restrict__ D8, float* __restrict__ rowsum, float* __restrict__ rowsq)
{
    const int ib = blockIdx.x * 4;
    const int t  = threadIdx.x;
    {   // zero accumulators (stream-ordered before k2/k5)
        const int tp = blockIdx.x*256 + t;      // grid*256 = 131072 = |D8|
        D8[tp] = 0.f;
        if      (tp < 2048) rowsum[tp] = 0.f;
        else if (tp < 4096) rowsq[tp - 2048] = 0.f;
    }
    __shared__ float xs[4][FIN];
    __shared__ float part[256];
    #pragma unroll
    for (int n = 0; n < 4; ++n) xs[n][t] = x[(long)(ib+n)*FIN + t];
    __syncthreads();
    float a0 = 0.f, a1 = 0.f, a2 = 0.f, a3 = 0.f;
    #pragma unroll 4
    for (int c = 0; c < FIN; ++c) {
        const float wv = Wv[c*FOUT + t];
        a0 = fmaf(xs[0][c], wv, a0); a1 = fmaf(xs[1][c], wv, a1);
        a2 = fmaf(xs[2][c], wv, a2); a3 = fmaf(xs[3][c], wv, a3);
    }
    ushort4 uv;
    uv.x = f2b(a0 * 0.0625f); uv.y = f2b(a1 * 0.0625f);
    uv.z = f2b(a2 * 0.0625f); uv.w = f2b(a3 * 0.0625f);
    *(ushort4*)&vtb[(long)t*NN + ib] = uv;
    {
        const int n = t >> 6, h = t & 7, seg = (t >> 3) & 7;
        float a = 0.f;
        for (int c = seg*32; c < seg*32 + 32; ++c)
            a = fmaf(xs[n][c], Wq[c*HH + h] + Wk[c*HH + h], a);
        part[t] = a;
    }
    __syncthreads();
    if (t < 32) {
        const int n = t >> 3, h = t & 7;
        float a = 0.f;
        #pragma unroll
        for (int s2 = 0; s2 < 8; ++s2) a += part[n*64 + s2*8 + h];
        qk[(ib+n)*HH + h] = a * (0.0625f * 0.35355339059327373f); // *scale/sqrt(8)
    }
}

// ------------------------------------------------- K2: denoms + f-field + dd
// Atomic contention fix: accumulate into D8[by&7][pair] (8-way bucketed).
__global__ __launch_bounds__(256) void k2_denom(
    const float* __restrict__ bond, const float* __restrict__ dist,
    const float* __restrict__ deg, const float* __restrict__ qk,
    const float* __restrict__ wb, const float* __restrict__ wbc,
    const float* __restrict__ wg, float* __restrict__ D8,
    unsigned short* __restrict__ fbuf, unsigned short* __restrict__ ddb)
{
    const float cb = wb[0] * wbc[0];
    const float cg = wg[0];
    const int t  = threadIdx.x;
    const int tx = t & 63;              // j-quad
    const int ty = t >> 6;              // 0..3 (i-subtile, 8 i each)
    const int j0 = blockIdx.x * 256;
    const int i0 = blockIdx.y * 32;
    const int j  = j0 + tx*4;
    __shared__ float qs[32*8];          // 1 KB
    __shared__ float red[4][2048];      // 32 KB
    for (int p = t; p < 256; p += 256) qs[p] = qk[i0*8 + p];
    __syncthreads();
    float acc[4][8];
    #pragma unroll
    for (int jj = 0; jj < 4; ++jj)
        #pragma unroll
        for (int h = 0; h < 8; ++h) acc[jj][h] = 0.f;
    const int ibase = i0 + ty*8;
    #pragma unroll
    for (int ii = 0; ii < 8; ++ii) {
        const long idx = (long)(ibase + ii)*NN + j;
        const float4 dv = *(const float4*)&dist[idx];
        const float4 bv = *(const float4*)&bond[idx];
        const float4 gv = *(const float4*)&deg[idx];
        ushort4 fb, db;
        fb.x = f2b((gv.x > 0.f) ? fmaf(cb, bv.x, cg*dv.x) : -__builtin_inff());
        fb.y = f2b((gv.y > 0.f) ? fmaf(cb, bv.y, cg*dv.y) : -__builtin_inff());
        fb.z = f2b((gv.z > 0.f) ? fmaf(cb, bv.z, cg*dv.z) : -__builtin_inff());
        fb.w = f2b((gv.w > 0.f) ? fmaf(cb, bv.w, cg*dv.w) : -__builtin_inff());
        db.x = f2b(-dv.x * gv.x); db.y = f2b(-dv.y * gv.y);
        db.z = f2b(-dv.z * gv.z); db.w = f2b(-dv.w * gv.w);
        *(ushort4*)&fbuf[idx] = fb;
        *(ushort4*)&ddb[idx]  = db;
        float s[4];
        s[0] = b2f(fb.x); s[1] = b2f(fb.y); s[2] = b2f(fb.z); s[3] = b2f(fb.w);
        const float* qrow = &qs[(ty*8 + ii)*8];
        #pragma unroll
        for (int h = 0; h < 8; ++h) {
            const float q = qrow[h];
            #pragma unroll
            for (int jj = 0; jj < 4; ++jj) {
                float r = q + s[jj];
                r = fmaxf(r, 0.2f*r);       // leaky_relu(r, 0.2)
                acc[jj][h] += __expf(r);    // masked: exp(-inf) = 0
            }
        }
    }
    #pragma unroll
    for (int jj = 0; jj < 4; ++jj)
        #pragma unroll
        for (int h = 0; h < 8; ++h) red[ty][(tx*4 + jj)*8 + h] = acc[jj][h];
    __syncthreads();
    const int bucket = (blockIdx.y & 7) << 14;   // 8 buckets of 16384
    for (int p = t; p < 2048; p += 256) {
        const float ssum = red[0][p] + red[1][p] + red[2][p] + red[3][p];
        atomicAdd(&D8[bucket + j0*8 + p], ssum);
    }
}

// --------------------------- K3: attn_mean -> bf16 (tile 32i x 256j, grid 512)
// Reduces D8's 8 buckets once per block into LDS (invD table).
__global__ __launch_bounds__(256) void k3_attnmean(
    const unsigned short* __restrict__ fbuf, const float* __restrict__ qk,
    const float* __restrict__ D8, unsigned short* __restrict__ amb)
{
    const int t  = threadIdx.x;
    const int tx = t & 63;
    const int ty = t >> 6;
    const int j0 = blockIdx.x * 256;
    const int i0 = blockIdx.y * 32;
    const int j  = j0 + tx*4;
    __shared__ float qs[32*8];
    __shared__ float Dred[2048];         // invD for this j0-slice (8 KB)
    for (int p = t; p < 256; p += 256) qs[p] = qk[i0*8 + p];
    for (int p = t; p < 2048; p += 256) {
        float s = 0.f;
        #pragma unroll
        for (int o = 0; o < 8; ++o) s += D8[(o << 14) + j0*8 + p];
        Dred[p] = 0.125f / fmaxf(s, 1e-30f);
    }
    __syncthreads();
    float invD[4][8];
    #pragma unroll
    for (int jj = 0; jj < 4; ++jj)
        #pragma unroll
        for (int h = 0; h < 8; ++h)
            invD[jj][h] = Dred[(tx*4 + jj)*8 + h];
    const int ibase = i0 + ty*8;
    #pragma unroll
    for (int ii = 0; ii < 8; ++ii) {
        const long idx = (long)(ibase + ii)*NN + j;
        const ushort4 fb = *(const ushort4*)&fbuf[idx];
        float s[4];
        s[0] = b2f(fb.x); s[1] = b2f(fb.y); s[2] = b2f(fb.z); s[3] = b2f(fb.w);
        float o[4] = {0.f, 0.f, 0.f, 0.f};
        const float* qrow = &qs[(ty*8 + ii)*8];
        #pragma unroll
        for (int h = 0; h < 8; ++h) {
            const float q = qrow[h];
            #pragma unroll
            for (int jj = 0; jj < 4; ++jj) {
                float r = q + s[jj];
                r = fmaxf(r, 0.2f*r);
                o[jj] = fmaf(__expf(r), invD[jj][h], o[jj]);  // masked -> 0
            }
        }
        ushort4 ob;
        ob.x = f2b(o[0]); ob.y = f2b(o[1]); ob.z = f2b(o[2]); ob.w = f2b(o[3]);
        *(ushort4*)&amb[idx] = ob;
    }
}

// --------------- K4: aggregated = amb @ vtb^T (full K) + elu -> out0, unb
// Wave tile 16i x 32f (2 MFMA/k-step): halves amb L3 traffic vs 16x16.
// 1024 waves = 256 blocks x 4 waves.
__global__ __launch_bounds__(256) void k4_aggr(
    const unsigned short* __restrict__ amb,
    const unsigned short* __restrict__ vtb,
    float* __restrict__ out0, unsigned short* __restrict__ unb)
{
    const int w = threadIdx.x >> 6, lane = threadIdx.x & 63;
    const int vw = blockIdx.x*4 + w;            // [0,1024)
    const int it = vw >> 3;                     // i-tile [0,128)
    const int f0 = (vw & 7) * 32;               // f-tile (32 wide)
    const int lm = lane & 15, lq = lane >> 4;
    const unsigned short* arow  = &amb[(long)(it*16 + lm)*NN + lq*8];
    const unsigned short* brow0 = &vtb[(long)(f0 + lm)*NN + lq*8];
    const unsigned short* brow1 = &vtb[(long)(f0 + 16 + lm)*NN + lq*8];
    f32x4 acc0 = {0.f, 0.f, 0.f, 0.f};
    f32x4 acc1 = {0.f, 0.f, 0.f, 0.f};
    #pragma unroll 4
    for (int kk = 0; kk < NN; kk += 32) {
        const bhalf8 a  = *(const bhalf8*)&arow[kk];
        const bhalf8 b0 = *(const bhalf8*)&brow0[kk];
        const bhalf8 b1 = *(const bhalf8*)&brow1[kk];
        acc0 = __builtin_amdgcn_mfma_f32_16x16x32_bf16(a, b0, acc0, 0, 0, 0);
        acc1 = __builtin_amdgcn_mfma_f32_16x16x32_bf16(a, b1, acc1, 0, 0, 0);
    }
    #pragma unroll
    for (int r = 0; r < 4; ++r) {
        const int i = it*16 + lq*4 + r;         // C/D: row=(l>>4)*4+reg
        float s0 = acc0[r], s1 = acc1[r];
        s0 = (s0 > 0.f) ? s0 : (__expf(s0) - 1.f);
        s1 = (s1 > 0.f) ? s1 : (__expf(s1) - 1.f);
        out0[(long)i*FOUT + f0 + lm]      = s0;
        out0[(long)i*FOUT + f0 + 16 + lm] = s1;
        unb [(long)i*FOUT + f0 + lm]      = f2b(s0);
        unb [(long)i*FOUT + f0 + 16 + lm] = f2b(s1);
    }
}

// -------- K5: sim = un@un^T via MFMA; c0 = bf16(sigmoid(sim)*ddb); row stats
__global__ __launch_bounds__(256) void k5_sim(
    const unsigned short* __restrict__ unb, const unsigned short* __restrict__ ddb,
    unsigned short* __restrict__ c0,
    float* __restrict__ rowsum, float* __restrict__ rowsq)
{
    const int i0 = blockIdx.y * 64;
    const int j0 = blockIdx.x * 64;
    const int w  = threadIdx.x >> 6;
    const int l  = threadIdx.x & 63;
    const int lm = l & 15, lq = l >> 4;
    const int iw = i0 + w*16;
    f32x4 acc[4] = {f32x4{0,0,0,0}, f32x4{0,0,0,0}, f32x4{0,0,0,0}, f32x4{0,0,0,0}};
    for (int kk = 0; kk < FOUT; kk += 32) {
        const bhalf8 a = *(const bhalf8*)&unb[(long)(iw + lm)*FOUT + kk + lq*8];
        #pragma unroll
        for (int c = 0; c < 4; ++c) {
            const bhalf8 b = *(const bhalf8*)&unb[(long)(j0 + c*16 + lm)*FOUT + kk + lq*8];
            acc[c] = __builtin_amdgcn_mfma_f32_16x16x32_bf16(a, b, acc[c], 0, 0, 0);
        }
    }
    float srow[4] = {0.f,0.f,0.f,0.f}, qrow[4] = {0.f,0.f,0.f,0.f};
    #pragma unroll
    for (int c = 0; c < 4; ++c) {
        #pragma unroll
        for (int r = 0; r < 4; ++r) {
            const int i = iw + lq*4 + r;
            const int j = j0 + c*16 + lm;
            const long idx = (long)i*NN + j;
            const float sg = 1.f / (1.f + __expf(-acc[c][r]));
            const float val = sg * b2f(ddb[idx]);        // ddb = -dist*deg
            c0[idx] = f2b(val);
            srow[r] += val;
            qrow[r] = fmaf(val, val, qrow[r]);
        }
    }
    #pragma unroll
    for (int r = 0; r < 4; ++r) {
        #pragma unroll
        for (int m = 8; m >= 1; m >>= 1) {
            srow[r] += __shfl_xor(srow[r], m, 64);
            qrow[r] += __shfl_xor(qrow[r], m, 64);
        }
        if (lm == 0) {
            atomicAdd(&rowsum[iw + lq*4 + r], srow[r]);
            atomicAdd(&rowsq [iw + lq*4 + r], qrow[r]);
        }
    }
}

// -------- K7: conn = norm(c0) + norm(c0)^T; stats computed from rowsum/rowsq
__global__ __launch_bounds__(256) void k7_conn(
    const unsigned short* __restrict__ c0, const float* __restrict__ rowsum,
    const float* __restrict__ rowsq, float* __restrict__ out1)
{
    const int i0 = blockIdx.y * 64;
    const int j0 = blockIdx.x * 64;
    const int t  = threadIdx.x;
    __shared__ float LT[64][68];     // LT[i_local][j_local] = c0[j0+jl][i0+il]
    __shared__ float mui[64], rii[64], muj[64], rsj[64];
    const int r  = t >> 4;
    const int c4 = (t & 15) * 4;
    if (t < 64) {
        const float m = rowsum[j0 + t] * (1.f/NN);
        muj[t] = m;
        rsj[t] = rsqrtf(rowsq[j0 + t]*(1.f/NN) - m*m + 1e-5f);
    } else if (t < 128) {
        const int rr = t - 64;
        const float m = rowsum[i0 + rr] * (1.f/NN);
        mui[rr] = m;
        rii[rr] = rsqrtf(rowsq[i0 + rr]*(1.f/NN) - m*m + 1e-5f);
    }
    #pragma unroll
    for (int p = 0; p < 4; ++p) {
        const int jl = r + p*16;
        const ushort4 q = *(const ushort4*)&c0[(long)(j0 + jl)*NN + i0 + c4];
        LT[c4+0][jl] = b2f(q.x); LT[c4+1][jl] = b2f(q.y);
        LT[c4+2][jl] = b2f(q.z); LT[c4+3][jl] = b2f(q.w);
    }
    __syncthreads();
    #pragma unroll
    for (int p = 0; p < 4; ++p) {
        const int rr = r + p*16;
        const int i  = i0 + rr;
        const ushort4 xb = *(const ushort4*)&c0[(long)i*NN + j0 + c4];
        const float mi = mui[rr], ri = rii[rr];
        float4 o;
        o.x = (b2f(xb.x) - mi)*ri + (LT[rr][c4+0] - muj[c4+0])*rsj[c4+0];
        o.y = (b2f(xb.y) - mi)*ri + (LT[rr][c4+1] - muj[c4+1])*rsj[c4+1];
        o.z = (b2f(xb.z) - mi)*ri + (LT[rr][c4+2] - muj[c4+2])*rsj[c4+2];
        o.w = (b2f(xb.w) - mi)*ri + (LT[rr][c4+3] - muj[c4+3])*rsj[c4+3];
        *(float4*)&out1[(long)i*NN + j0 + c4] = o;
    }
}

extern "C" void kernel_launch(void* const* d_in, const int* in_sizes, int n_in,
                              void* d_out, int out_size, void* d_ws, size_t ws_size,
                              hipStream_t stream)
{
    const float* x    = (const float*)d_in[0];
    const float* dist = (const float*)d_in[1];
    const float* bond = (const float*)d_in[2];
    // d_in[3] edge_direction: unused (only l=0 component couples; Y_0 = 1)
    const float* deg  = (const float*)d_in[4];
    const float* Wq   = (const float*)d_in[5];
    const float* Wk   = (const float*)d_in[6];
    const float* Wv   = (const float*)d_in[7];
    const float* wb   = (const float*)d_in[8];
    const float* wbc  = (const float*)d_in[9];
    const float* wg   = (const float*)d_in[10];

    float* out0 = (float*)d_out;            // updated_nodes: 2048*256 fp32
    float* out1 = out0 + (size_t)NN*FOUT;   // conn: 2048*2048 fp32

    char* w = (char*)d_ws;
    unsigned short* fbuf_c0 = (unsigned short*)(w);           //  8,388,608 B
    unsigned short* amb  = (unsigned short*)(w +  8388608);   //  8,388,608 B
    unsigned short* ddb  = (unsigned short*)(w + 16777216);   //  8,388,608 B
    unsigned short* vtb  = (unsigned short*)(w + 25165824);   //  1,048,576 B
    unsigned short* unb  = (unsigned short*)(w + 26214400);   //  1,048,576 B
    float* qk      = (float*)(w + 27262976);                  //     65,536 B
    float* D8      = (float*)(w + 27328512);                  //    524,288 B (8 buckets)
    float* rowsum  = (float*)(w + 27852800);                  //      8,192 B
    float* rowsq   = (float*)(w + 27860992);                  //      8,192 B

    k1_qkv<<<NN/4, 256, 0, stream>>>(x, Wq, Wk, Wv, vtb, qk, D8, rowsum, rowsq);
    dim3 g23(NN/256, NN/32);
    k2_denom<<<g23, 256, 0, stream>>>(bond, dist, deg, qk, wb, wbc, wg, D8, fbuf_c0, ddb);
    k3_attnmean<<<g23, 256, 0, stream>>>(fbuf_c0, qk, D8, amb);
    k4_aggr<<<NN/8, 256, 0, stream>>>(amb, vtb, out0, unb);
    dim3 g5(NN/64, NN/64);
    k5_sim<<<g5, 256, 0, stream>>>(unb, ddb, fbuf_c0, rowsum, rowsq);
    k7_conn<<<g5, 256, 0, stream>>>(fbuf_c0, rowsum, rowsq, out1);
}